// Round 10
// baseline (382.325 us; speedup 1.0000x reference)
//
#include <hip/hip_runtime.h>
#include <hip/hip_fp16.h>

#define NN 100000      // nodes
#define NE 1600000     // edges
#define INC 128        // in channels
#define HID 96         // hidden
#define NG 512         // graphs

#define GEMM1_BLOCKS 1563        // ceil(NN/64)
#define REORDER_BLOCKS 6250      // ceil(NE/256)
#define G2_BLOCKS 1563           // ceil(NN/64) for MFMA gemm2 (64 rows/block)
#define ZERO_BLOCKS 392          // ceil((NN+1)/256)

typedef _Float16 half8 __attribute__((ext_vector_type(8)));
typedef float f32x4 __attribute__((ext_vector_type(4)));

// ---------------- zero off  +  pack W2 f32->fp16 fragment-order ----------------
// W2frag[((kc*6+ct)*64 + l)*8 + i] = W2[kc*32 + (l>>4)*8 + i][ct*16 + (l&15)]
__global__ void k_zero_pack(int* __restrict__ off, const float* __restrict__ W2,
                            __half* __restrict__ W2frag) {
    if (blockIdx.x < ZERO_BLOCKS) {
        int i = blockIdx.x * 256 + threadIdx.x;
        if (i < NN + 1) off[i] = 0;
        return;
    }
    int p = (blockIdx.x - ZERO_BLOCKS) * 256 + threadIdx.x;   // (kc,ct,l) id
    if (p >= 3 * 6 * 64) return;
    int kc = p / 384;
    int rem = p - kc * 384;
    int ct = rem >> 6;
    int l = rem & 63;
#pragma unroll
    for (int i = 0; i < 8; ++i) {
        int k = kc * 32 + ((l >> 4) << 3) + i;
        int c = ct * 16 + (l & 15);
        W2frag[p * 8 + i] = __float2half(W2[k * HID + c]);
    }
}

__global__ void k_hist(const int* __restrict__ dst, int* __restrict__ off) {
    int e = blockIdx.x * blockDim.x + threadIdx.x;
    if (e < NE) atomicAdd(&off[dst[e] + 1], 1);
}

// scan phase 1 + dis (from pre-scan degree) + cur zeroing
__global__ __launch_bounds__(256) void k_scan1(int* __restrict__ a, int* __restrict__ bsum,
                                               float* __restrict__ dis, int* __restrict__ cur,
                                               int n) {
    __shared__ int s[256];
    int base = blockIdx.x * 1024 + threadIdx.x * 4;
    int o0 = (base + 0 < n) ? a[base + 0] : 0;
    int o1 = (base + 1 < n) ? a[base + 1] : 0;
    int o2 = (base + 2 < n) ? a[base + 2] : 0;
    int o3 = (base + 3 < n) ? a[base + 3] : 0;
    // dis[idx-1] = rsqrt(deg + 1), deg = pre-scan a[idx]
    if (base + 0 >= 1 && base + 0 < n) dis[base - 1] = rsqrtf((float)(o0 + 1));
    if (base + 1 < n) dis[base + 0] = rsqrtf((float)(o1 + 1));
    if (base + 2 < n) dis[base + 1] = rsqrtf((float)(o2 + 1));
    if (base + 3 < n) dis[base + 2] = rsqrtf((float)(o3 + 1));
#pragma unroll
    for (int j = 0; j < 4; ++j) {
        int idx = base + j;
        if (idx < NN) cur[idx] = 0;
    }
    int v0 = o0, v1 = o1 + v0, v2 = o2 + v1, v3 = o3 + v2;
    s[threadIdx.x] = v3;
    __syncthreads();
    for (int ofs = 1; ofs < 256; ofs <<= 1) {
        int t = (threadIdx.x >= ofs) ? s[threadIdx.x - ofs] : 0;
        __syncthreads();
        s[threadIdx.x] += t;
        __syncthreads();
    }
    int pre = (threadIdx.x > 0) ? s[threadIdx.x - 1] : 0;
    v0 += pre; v1 += pre; v2 += pre; v3 += pre;
    if (base + 0 < n) a[base + 0] = v0;
    if (base + 1 < n) a[base + 1] = v1;
    if (base + 2 < n) a[base + 2] = v2;
    if (base + 3 < n) a[base + 3] = v3;
    if (threadIdx.x == 255) bsum[blockIdx.x] = s[255];
}

// scan phase 2+3 fused: each block reduces raw bsum[0..b) itself then adds
__global__ __launch_bounds__(256) void k_scan3(int* __restrict__ a, const int* __restrict__ bsum,
                                               int n) {
    int b = blockIdx.x;
    if (b == 0) return;
    __shared__ int red[256];
    int t = threadIdx.x;
    red[t] = (t < b) ? bsum[t] : 0;
    __syncthreads();
    for (int s2 = 128; s2; s2 >>= 1) {
        if (t < s2) red[t] += red[t + s2];
        __syncthreads();
    }
    int add = red[0];
    int base = b * 1024 + t * 4;
#pragma unroll
    for (int j = 0; j < 4; ++j) {
        int idx = base + j;
        if (idx < n) a[idx] += add;
    }
}

// ---------------- FUSED: gemm1 (compute-bound) ∥ reorder (write-bound) ----------------
__global__ __launch_bounds__(256) void k_gemm1_reorder(
        const float* __restrict__ X, const float* __restrict__ W, __half* __restrict__ Yh,
        const int* __restrict__ src, const int* __restrict__ dst,
        const int* __restrict__ off, int* __restrict__ cur,
        const float* __restrict__ dis, int2* __restrict__ ssrcw) {
    __shared__ float xsT[32][64];   // X tile, transposed
    __shared__ float ws[32 * 96];   // W tile
    const int tid = threadIdx.x;

    if (blockIdx.x >= GEMM1_BLOCKS) {
        // -------- reorder body --------
        int e = (blockIdx.x - GEMM1_BLOCKS) * 256 + tid;
        if (e < NE) {
            int s = src[e], d = dst[e];
            int p = off[d] + atomicAdd(&cur[d], 1);
            float w = dis[s] * dis[d];
            ssrcw[p] = make_int2(s, __float_as_int(w));
        }
        return;
    }

    // -------- gemm body (K = INC = 128) --------
    const int row0 = blockIdx.x * 64;
    const int rg = tid >> 4;        // 0..15
    const int cg = tid & 15;        // 0..15
    const int r0 = rg * 4, c0 = cg * 6;
    float acc[4][6] = {};
    const int srow = tid & 63;      // staging row
    const int sq = tid >> 6;        // 0..3

    for (int k0 = 0; k0 < INC; k0 += 32) {
        {
            int grow = row0 + srow;
            float4 v = make_float4(0.f, 0.f, 0.f, 0.f);
            float4 u = make_float4(0.f, 0.f, 0.f, 0.f);
            if (grow < NN) {
                v = *(const float4*)&X[(size_t)grow * INC + k0 + sq * 4];
                u = *(const float4*)&X[(size_t)grow * INC + k0 + (sq + 4) * 4];
            }
            xsT[sq * 4 + 0][srow] = v.x;
            xsT[sq * 4 + 1][srow] = v.y;
            xsT[sq * 4 + 2][srow] = v.z;
            xsT[sq * 4 + 3][srow] = v.w;
            xsT[(sq + 4) * 4 + 0][srow] = u.x;
            xsT[(sq + 4) * 4 + 1][srow] = u.y;
            xsT[(sq + 4) * 4 + 2][srow] = u.z;
            xsT[(sq + 4) * 4 + 3][srow] = u.w;
        }
        {
            const float4* wsrc = (const float4*)(W + k0 * 96);
            float4* wdst = (float4*)ws;
            wdst[tid] = wsrc[tid];
            wdst[tid + 256] = wsrc[tid + 256];
            wdst[tid + 512] = wsrc[tid + 512];
        }
        __syncthreads();
#pragma unroll
        for (int kk = 0; kk < 32; ++kk) {
            float4 xv = *(const float4*)&xsT[kk][r0];
            float wv[6];
            *(float2*)&wv[0] = *(const float2*)&ws[kk * 96 + c0];
            *(float2*)&wv[2] = *(const float2*)&ws[kk * 96 + c0 + 2];
            *(float2*)&wv[4] = *(const float2*)&ws[kk * 96 + c0 + 4];
            float xr[4] = {xv.x, xv.y, xv.z, xv.w};
#pragma unroll
            for (int i = 0; i < 4; ++i)
#pragma unroll
                for (int j = 0; j < 6; ++j) acc[i][j] += xr[i] * wv[j];
        }
        __syncthreads();
    }
#pragma unroll
    for (int i = 0; i < 4; ++i) {
        int grow = row0 + r0 + i;
        if (grow >= NN) break;
        __half2* yp = (__half2*)&Yh[(size_t)grow * HID + c0];
        yp[0] = __floats2half2_rn(acc[i][0], acc[i][1]);
        yp[1] = __floats2half2_rn(acc[i][2], acc[i][3]);
        yp[2] = __floats2half2_rn(acc[i][4], acc[i][5]);
    }
}

// ---------------- GEMM2 (MFMA fp16) ∥ pool1 (H1 partials, hidden) ----------------
// gemm2 blocks: 4 waves x 16 rows, K=96 in 3 steps of 32, mfma_f32_16x16x32_f16.
// pool1 blocks (>= G2_BLOCKS): per-graph sum/max over H1h features 0..95.
__global__ __launch_bounds__(256) void k_gemm2_pool1(
        const __half* __restrict__ Xh, const __half* __restrict__ W2frag,
        __half* __restrict__ Yh, const int* __restrict__ batch,
        float* __restrict__ p1sum, float* __restrict__ p1max) {
    __shared__ char smem[18432];    // 9216 fp16 W2 frags | pool partials
    const int tid = threadIdx.x;

    if (blockIdx.x >= G2_BLOCKS) {
        // -------- pool1 body --------
        int g = blockIdx.x - G2_BLOCKS;
        float* ps = (float*)smem;          // [2][96]
        float* pm = ps + 192;              // [2][96]
        int lo = 0, hi = NN;
        while (lo < hi) { int mid = (lo + hi) >> 1; if (batch[mid] < g) lo = mid + 1; else hi = mid; }
        int start = lo;
        hi = NN;
        while (lo < hi) { int mid = (lo + hi) >> 1; if (batch[mid] < g + 1) lo = mid + 1; else hi = mid; }
        int end = lo;
        if (tid < 192) {
            int way = tid / 96, f = tid - way * 96;
            float sum = 0.f, mx = 0.f;
            for (int n = start + way; n < end; n += 2) {
                float v = __half2float(Xh[(size_t)n * HID + f]);
                sum += v;
                mx = fmaxf(mx, v);
            }
            ps[way * 96 + f] = sum;
            pm[way * 96 + f] = mx;
        }
        __syncthreads();
        if (tid < 96) {
            p1sum[g * 96 + tid] = ps[tid] + ps[96 + tid];
            p1max[g * 96 + tid] = fmaxf(pm[tid], pm[96 + tid]);
        }
        return;
    }

    // -------- gemm2 MFMA body --------
    __half* w2s = (__half*)smem;
    {
        half8* d8 = (half8*)w2s;
        const half8* s8 = (const half8*)W2frag;
        for (int i = tid; i < 1152; i += 256) d8[i] = s8[i];
    }
    __syncthreads();
    const int w = tid >> 6;          // wave 0..3
    const int l = tid & 63;          // lane
    const int row0 = blockIdx.x * 64 + w * 16;
    int arow = row0 + (l & 15);
    if (arow >= NN) arow = NN - 1;   // clamp (stores guarded)
    f32x4 acc[6] = {};
#pragma unroll
    for (int kc = 0; kc < 3; ++kc) {
        half8 a = *(const half8*)&Xh[(size_t)arow * HID + kc * 32 + ((l >> 4) << 3)];
#pragma unroll
        for (int ct = 0; ct < 6; ++ct) {
            half8 b = *(const half8*)&w2s[((kc * 6 + ct) * 64 + l) * 8];
            acc[ct] = __builtin_amdgcn_mfma_f32_16x16x32_f16(a, b, acc[ct], 0, 0, 0);
        }
    }
    // C layout (m89-verified): col = lane&15, row = (lane>>4)*4 + i
    const int orow = row0 + ((l >> 4) << 2);
    const int col = l & 15;
#pragma unroll
    for (int ct = 0; ct < 6; ++ct)
#pragma unroll
        for (int i = 0; i < 4; ++i) {
            int r = orow + i;
            if (r < NN) Yh[(size_t)r * HID + ct * 16 + col] = __float2half(acc[ct][i]);
        }
}

// ---------------- fused GCN aggregation + node-logit partial ----------------
// 32 threads per destination node; thread t owns features {t, t+32, t+64}.
// PHASE 1: nodeOut[d] = bn + h1 . Wn[0:96]      PHASE 2: nodeOut[d] += h2 . Wn[96:192]
template <int PHASE>
__global__ __launch_bounds__(256) void k_agg(const __half* __restrict__ Ah,
                                             const int2* __restrict__ ssrcw,
                                             const int* __restrict__ off,
                                             const float* __restrict__ dis,
                                             const float* __restrict__ bias,
                                             const float* __restrict__ Wn,
                                             const float* __restrict__ bn,
                                             __half* __restrict__ outh,
                                             float* __restrict__ nodeOut) {
    int gid = blockIdx.x * blockDim.x + threadIdx.x;
    int d = gid >> 5;
    int t = gid & 31;
    if (d >= NN) return;
    const int beg = off[d], end = off[d + 1];
    const float dd = dis[d];
    const __half* ad = Ah + (size_t)d * HID;
    float acc0 = __half2float(ad[t]) * dd * dd;
    float acc1 = __half2float(ad[t + 32]) * dd * dd;
    float acc2 = __half2float(ad[t + 64]) * dd * dd;
    int j = beg;
    for (; j + 7 < end; j += 8) {
        int2 e[8];
#pragma unroll
        for (int q = 0; q < 8; ++q) e[q] = ssrcw[j + q];
        float w[8];
        const __half* ap[8];
#pragma unroll
        for (int q = 0; q < 8; ++q) {
            w[q] = __int_as_float(e[q].y);
            ap[q] = Ah + (size_t)e[q].x * HID;
        }
        float g0[8], g1[8], g2[8];
#pragma unroll
        for (int q = 0; q < 8; ++q) {
            g0[q] = __half2float(ap[q][t]);
            g1[q] = __half2float(ap[q][t + 32]);
            g2[q] = __half2float(ap[q][t + 64]);
        }
#pragma unroll
        for (int q = 0; q < 8; ++q) {
            acc0 += g0[q] * w[q];
            acc1 += g1[q] * w[q];
            acc2 += g2[q] * w[q];
        }
    }
    for (; j < end; ++j) {
        int2 e0 = ssrcw[j];
        float w0 = __int_as_float(e0.y);
        const __half* a0 = Ah + (size_t)e0.x * HID;
        acc0 += __half2float(a0[t]) * w0;
        acc1 += __half2float(a0[t + 32]) * w0;
        acc2 += __half2float(a0[t + 64]) * w0;
    }
    float h0 = fmaxf(acc0 + bias[t], 0.f);
    float h1v = fmaxf(acc1 + bias[t + 32], 0.f);
    float h2v = fmaxf(acc2 + bias[t + 64], 0.f);
    __half* o = outh + (size_t)d * HID;
    o[t] = __float2half(h0);
    o[t + 32] = __float2half(h1v);
    o[t + 64] = __float2half(h2v);

    const int woff = (PHASE == 1) ? 0 : 96;
    float partial = h0 * Wn[woff + t] + h1v * Wn[woff + t + 32] + h2v * Wn[woff + t + 64];
#pragma unroll
    for (int m = 16; m; m >>= 1) partial += __shfl_down(partial, m, 32);
    if (t == 0) {
        if (PHASE == 1) nodeOut[d] = partial + bn[0];
        else            nodeOut[d] += partial;
    }
}

// ---------------- pool2: H2 partials + combine + graph head ----------------
__global__ __launch_bounds__(256) void k_pool2(const __half* __restrict__ H2h,
                                               const int* __restrict__ batch,
                                               const float* __restrict__ p1sum,
                                               const float* __restrict__ p1max,
                                               const float* __restrict__ Wg,
                                               const float* __restrict__ bg,
                                               float* __restrict__ out) {
    int g = blockIdx.x;
    int tid = threadIdx.x;
    __shared__ float ps[192], pm[192], contrib[96];
    int lo = 0, hi = NN;
    while (lo < hi) { int mid = (lo + hi) >> 1; if (batch[mid] < g) lo = mid + 1; else hi = mid; }
    int start = lo;
    hi = NN;
    while (lo < hi) { int mid = (lo + hi) >> 1; if (batch[mid] < g + 1) lo = mid + 1; else hi = mid; }
    int end = lo;
    if (tid < 192) {
        int way = tid / 96, f = tid - way * 96;
        float sum = 0.f, mx = 0.f;
        for (int n = start + way; n < end; n += 2) {
            float v = __half2float(H2h[(size_t)n * HID + f]);
            sum += v;
            mx = fmaxf(mx, v);
        }
        ps[way * 96 + f] = sum;
        pm[way * 96 + f] = mx;
    }
    __syncthreads();
    if (tid < 96) {
        float s2 = ps[tid] + ps[96 + tid];
        float m2 = fmaxf(pm[tid], pm[96 + tid]);
        float icnt = 1.0f / fmaxf((float)(end - start), 1.0f);
        contrib[tid] = p1sum[g * 96 + tid] * icnt * Wg[tid] +
                       s2 * icnt * Wg[96 + tid] +
                       p1max[g * 96 + tid] * Wg[192 + tid] +
                       m2 * Wg[288 + tid];
    }
    __syncthreads();
    if (tid < 32) {
        float acc = contrib[tid] + contrib[tid + 32] + contrib[tid + 64];
#pragma unroll
        for (int m = 16; m; m >>= 1) acc += __shfl_down(acc, m, 32);
        if (tid == 0) out[g] = acc + bg[0];
    }
}

extern "C" void kernel_launch(void* const* d_in, const int* in_sizes, int n_in,
                              void* d_out, int out_size, void* d_ws, size_t ws_size,
                              hipStream_t stream) {
    const float* x    = (const float*)d_in[0];
    const int*   ei   = (const int*)d_in[1];
    const int*   srcp = ei;
    const int*   dstp = ei + NE;
    const int*   batch = (const int*)d_in[2];
    const float* W1 = (const float*)d_in[3];
    const float* b1 = (const float*)d_in[4];
    const float* W2 = (const float*)d_in[5];
    const float* b2 = (const float*)d_in[6];
    const float* Wn = (const float*)d_in[7];
    const float* bn = (const float*)d_in[8];
    const float* Wg = (const float*)d_in[9];
    const float* bg = (const float*)d_in[10];
    float* out = (float*)d_out;

    char* p = (char*)d_ws;
    auto alloc = [&](size_t bytes) {
        char* r = p;
        p += (bytes + 255) & ~(size_t)255;
        return (void*)r;
    };
    float*  dis    = (float*)alloc(NN * 4);
    int*    off    = (int*)alloc((NN + 1) * 4);
    int*    cur    = (int*)alloc(NN * 4);
    int*    bsum   = (int*)alloc(128 * 4);
    int2*   ssrcw  = (int2*)alloc((size_t)NE * 8);
    __half* Ah     = (__half*)alloc((size_t)NN * HID * 2);   // hw buffer (both convs)
    __half* H1h    = (__half*)alloc((size_t)NN * HID * 2);
    __half* H2h    = (__half*)alloc((size_t)NN * HID * 2);
    __half* W2frag = (__half*)alloc(9216 * 2);
    float*  p1sum  = (float*)alloc((size_t)NG * 96 * 4);
    float*  p1max  = (float*)alloc((size_t)NG * 96 * 4);

    const int TPB = 256;
    const int nScan = NN + 1;
    const int nbScan = (nScan + 1023) / 1024;    // 98

    // prelude: zero off + pack W2 frags; hist; scan(+dis+cur-zero); scan-add
    k_zero_pack<<<ZERO_BLOCKS + 5, TPB, 0, stream>>>(off, W2, W2frag);
    k_hist<<<(NE + TPB - 1) / TPB, TPB, 0, stream>>>(dstp, off);
    k_scan1<<<nbScan, 256, 0, stream>>>(off, bsum, dis, cur, nScan);
    k_scan3<<<nbScan, 256, 0, stream>>>(off, bsum, nScan);

    // FUSED: gemm1 (blocks 0..1562)  ∥  reorder (blocks 1563..7812)
    k_gemm1_reorder<<<GEMM1_BLOCKS + REORDER_BLOCKS, 256, 0, stream>>>(
        x, W1, Ah, srcp, dstp, off, cur, dis, ssrcw);

    const int aggThreads = NN * 32;
    float* nodeOut = out + NG;

    // conv1 aggregate: H1h = fp16(relu(agg(Ah) + b1)) ; nodeOut = bn + h1.Wn[:96]
    k_agg<1><<<(aggThreads + TPB - 1) / TPB, TPB, 0, stream>>>(Ah, ssrcw, off, dis, b1, Wn, bn, H1h, nodeOut);

    // conv2 transform (MFMA) ∥ pool1 partials over H1h
    k_gemm2_pool1<<<G2_BLOCKS + NG, 256, 0, stream>>>(H1h, W2frag, Ah, batch, p1sum, p1max);

    // conv2 aggregate: H2h = fp16(relu(agg(Ah) + b2)) ; nodeOut += h2.Wn[96:]
    k_agg<2><<<(aggThreads + TPB - 1) / TPB, TPB, 0, stream>>>(Ah, ssrcw, off, dis, b2, Wn, bn, H2h, nodeOut);

    // pool2: H2 partials + combine + graph head
    k_pool2<<<NG, 256, 0, stream>>>(H2h, batch, p1sum, p1max, Wg, bg, out);
}

// Round 11
// 327.609 us; speedup vs baseline: 1.1670x; 1.1670x over previous
//
#include <hip/hip_runtime.h>
#include <hip/hip_fp16.h>

#define NN 100000      // nodes
#define NE 1600000     // edges
#define INC 128        // in channels
#define HID 96         // hidden
#define NG 512         // graphs

#define GEMM1_BLOCKS 1563        // ceil(NN/64)
#define REORDER_BLOCKS 6250      // ceil(NE/256)
#define G2_BLOCKS 1563           // ceil(NN/64) for MFMA gemm2
#define ZERO_BLOCKS 392          // ceil((NN+1)/256)

typedef _Float16 half8 __attribute__((ext_vector_type(8)));
typedef float f32x4 __attribute__((ext_vector_type(4)));

// ---------------- zero off  +  pack W2 f32->fp16 fragment-order ----------------
// W2frag[((kc*6+ct)*64 + l)*8 + i] = W2[kc*32 + (l>>4)*8 + i][ct*16 + (l&15)]
__global__ void k_zero_pack(int* __restrict__ off, const float* __restrict__ W2,
                            __half* __restrict__ W2frag) {
    if (blockIdx.x < ZERO_BLOCKS) {
        int i = blockIdx.x * 256 + threadIdx.x;
        if (i < NN + 1) off[i] = 0;
        return;
    }
    int p = (blockIdx.x - ZERO_BLOCKS) * 256 + threadIdx.x;   // (kc,ct,l) id
    if (p >= 3 * 6 * 64) return;
    int kc = p / 384;
    int rem = p - kc * 384;
    int ct = rem >> 6;
    int l = rem & 63;
#pragma unroll
    for (int i = 0; i < 8; ++i) {
        int k = kc * 32 + ((l >> 4) << 3) + i;
        int c = ct * 16 + (l & 15);
        W2frag[p * 8 + i] = __float2half(W2[k * HID + c]);
    }
}

__global__ void k_hist(const int* __restrict__ dst, int* __restrict__ off) {
    int e = blockIdx.x * blockDim.x + threadIdx.x;
    if (e < NE) atomicAdd(&off[dst[e] + 1], 1);
}

// scan phase 1 + dis (from pre-scan degree) + cur zeroing
__global__ __launch_bounds__(256) void k_scan1(int* __restrict__ a, int* __restrict__ bsum,
                                               float* __restrict__ dis, int* __restrict__ cur,
                                               int n) {
    __shared__ int s[256];
    int base = blockIdx.x * 1024 + threadIdx.x * 4;
    int o0 = (base + 0 < n) ? a[base + 0] : 0;
    int o1 = (base + 1 < n) ? a[base + 1] : 0;
    int o2 = (base + 2 < n) ? a[base + 2] : 0;
    int o3 = (base + 3 < n) ? a[base + 3] : 0;
    if (base + 0 >= 1 && base + 0 < n) dis[base - 1] = rsqrtf((float)(o0 + 1));
    if (base + 1 < n) dis[base + 0] = rsqrtf((float)(o1 + 1));
    if (base + 2 < n) dis[base + 1] = rsqrtf((float)(o2 + 1));
    if (base + 3 < n) dis[base + 2] = rsqrtf((float)(o3 + 1));
#pragma unroll
    for (int j = 0; j < 4; ++j) {
        int idx = base + j;
        if (idx < NN) cur[idx] = 0;
    }
    int v0 = o0, v1 = o1 + v0, v2 = o2 + v1, v3 = o3 + v2;
    s[threadIdx.x] = v3;
    __syncthreads();
    for (int ofs = 1; ofs < 256; ofs <<= 1) {
        int t = (threadIdx.x >= ofs) ? s[threadIdx.x - ofs] : 0;
        __syncthreads();
        s[threadIdx.x] += t;
        __syncthreads();
    }
    int pre = (threadIdx.x > 0) ? s[threadIdx.x - 1] : 0;
    v0 += pre; v1 += pre; v2 += pre; v3 += pre;
    if (base + 0 < n) a[base + 0] = v0;
    if (base + 1 < n) a[base + 1] = v1;
    if (base + 2 < n) a[base + 2] = v2;
    if (base + 3 < n) a[base + 3] = v3;
    if (threadIdx.x == 255) bsum[blockIdx.x] = s[255];
}

// scan phase 2+3 fused
__global__ __launch_bounds__(256) void k_scan3(int* __restrict__ a, const int* __restrict__ bsum,
                                               int n) {
    int b = blockIdx.x;
    if (b == 0) return;
    __shared__ int red[256];
    int t = threadIdx.x;
    red[t] = (t < b) ? bsum[t] : 0;
    __syncthreads();
    for (int s2 = 128; s2; s2 >>= 1) {
        if (t < s2) red[t] += red[t + s2];
        __syncthreads();
    }
    int add = red[0];
    int base = b * 1024 + t * 4;
#pragma unroll
    for (int j = 0; j < 4; ++j) {
        int idx = base + j;
        if (idx < n) a[idx] += add;
    }
}

// ---------------- FUSED: gemm1 (compute-bound) ∥ reorder (write-bound) ----------------
__global__ __launch_bounds__(256) void k_gemm1_reorder(
        const float* __restrict__ X, const float* __restrict__ W, __half* __restrict__ Yh,
        const int* __restrict__ src, const int* __restrict__ dst,
        const int* __restrict__ off, int* __restrict__ cur,
        const float* __restrict__ dis, int2* __restrict__ ssrcw) {
    __shared__ float xsT[32][64];   // X tile, transposed
    __shared__ float ws[32 * 96];   // W tile
    const int tid = threadIdx.x;

    if (blockIdx.x >= GEMM1_BLOCKS) {
        int e = (blockIdx.x - GEMM1_BLOCKS) * 256 + tid;
        if (e < NE) {
            int s = src[e], d = dst[e];
            int p = off[d] + atomicAdd(&cur[d], 1);
            float w = dis[s] * dis[d];
            ssrcw[p] = make_int2(s, __float_as_int(w));
        }
        return;
    }

    const int row0 = blockIdx.x * 64;
    const int rg = tid >> 4;
    const int cg = tid & 15;
    const int r0 = rg * 4, c0 = cg * 6;
    float acc[4][6] = {};
    const int srow = tid & 63;
    const int sq = tid >> 6;

    for (int k0 = 0; k0 < INC; k0 += 32) {
        {
            int grow = row0 + srow;
            float4 v = make_float4(0.f, 0.f, 0.f, 0.f);
            float4 u = make_float4(0.f, 0.f, 0.f, 0.f);
            if (grow < NN) {
                v = *(const float4*)&X[(size_t)grow * INC + k0 + sq * 4];
                u = *(const float4*)&X[(size_t)grow * INC + k0 + (sq + 4) * 4];
            }
            xsT[sq * 4 + 0][srow] = v.x;
            xsT[sq * 4 + 1][srow] = v.y;
            xsT[sq * 4 + 2][srow] = v.z;
            xsT[sq * 4 + 3][srow] = v.w;
            xsT[(sq + 4) * 4 + 0][srow] = u.x;
            xsT[(sq + 4) * 4 + 1][srow] = u.y;
            xsT[(sq + 4) * 4 + 2][srow] = u.z;
            xsT[(sq + 4) * 4 + 3][srow] = u.w;
        }
        {
            const float4* wsrc = (const float4*)(W + k0 * 96);
            float4* wdst = (float4*)ws;
            wdst[tid] = wsrc[tid];
            wdst[tid + 256] = wsrc[tid + 256];
            wdst[tid + 512] = wsrc[tid + 512];
        }
        __syncthreads();
#pragma unroll
        for (int kk = 0; kk < 32; ++kk) {
            float4 xv = *(const float4*)&xsT[kk][r0];
            float wv[6];
            *(float2*)&wv[0] = *(const float2*)&ws[kk * 96 + c0];
            *(float2*)&wv[2] = *(const float2*)&ws[kk * 96 + c0 + 2];
            *(float2*)&wv[4] = *(const float2*)&ws[kk * 96 + c0 + 4];
            float xr[4] = {xv.x, xv.y, xv.z, xv.w};
#pragma unroll
            for (int i = 0; i < 4; ++i)
#pragma unroll
                for (int j = 0; j < 6; ++j) acc[i][j] += xr[i] * wv[j];
        }
        __syncthreads();
    }
#pragma unroll
    for (int i = 0; i < 4; ++i) {
        int grow = row0 + r0 + i;
        if (grow >= NN) break;
        __half2* yp = (__half2*)&Yh[(size_t)grow * HID + c0];
        yp[0] = __floats2half2_rn(acc[i][0], acc[i][1]);
        yp[1] = __floats2half2_rn(acc[i][2], acc[i][3]);
        yp[2] = __floats2half2_rn(acc[i][4], acc[i][5]);
    }
}

// ---------------- GEMM2 (MFMA fp16, standalone; layout HW-validated round 10) ----------------
__global__ __launch_bounds__(256) void k_gemm2(const __half* __restrict__ Xh,
                                               const __half* __restrict__ W2frag,
                                               __half* __restrict__ Yh) {
    __shared__ __half w2s[9216];
    const int tid = threadIdx.x;
    {
        half8* d8 = (half8*)w2s;
        const half8* s8 = (const half8*)W2frag;
        for (int i = tid; i < 1152; i += 256) d8[i] = s8[i];
    }
    __syncthreads();
    const int w = tid >> 6;
    const int l = tid & 63;
    const int row0 = blockIdx.x * 64 + w * 16;
    int arow = row0 + (l & 15);
    if (arow >= NN) arow = NN - 1;
    f32x4 acc[6] = {};
#pragma unroll
    for (int kc = 0; kc < 3; ++kc) {
        half8 a = *(const half8*)&Xh[(size_t)arow * HID + kc * 32 + ((l >> 4) << 3)];
#pragma unroll
        for (int ct = 0; ct < 6; ++ct) {
            half8 b = *(const half8*)&w2s[((kc * 6 + ct) * 64 + l) * 8];
            acc[ct] = __builtin_amdgcn_mfma_f32_16x16x32_f16(a, b, acc[ct], 0, 0, 0);
        }
    }
    const int orow = row0 + ((l >> 4) << 2);
    const int col = l & 15;
#pragma unroll
    for (int ct = 0; ct < 6; ++ct)
#pragma unroll
        for (int i = 0; i < 4; ++i) {
            int r = orow + i;
            if (r < NN) Yh[(size_t)r * HID + ct * 16 + col] = __float2half(acc[ct][i]);
        }
}

// ---------------- fused GCN aggregation + node-logit partial (16 lanes/dst, half2) ------
// thread t in [0,16) owns half2 feature pairs {t, t+16, t+32} (features 2t.., 32+2t.., 64+2t..)
template <int PHASE>
__global__ __launch_bounds__(256) void k_agg(const __half* __restrict__ Ah,
                                             const int2* __restrict__ ssrcw,
                                             const int* __restrict__ off,
                                             const float* __restrict__ dis,
                                             const float* __restrict__ bias,
                                             const float* __restrict__ Wn,
                                             const float* __restrict__ bn,
                                             __half* __restrict__ outh,
                                             float* __restrict__ nodeOut) {
    int gid = blockIdx.x * blockDim.x + threadIdx.x;
    int d = gid >> 4;
    int t = gid & 15;
    if (d >= NN) return;
    const int beg = off[d], end = off[d + 1];
    const float dd = dis[d];
    const __half2* ad2 = (const __half2*)(Ah + (size_t)d * HID);
    float2 s0 = __half22float2(ad2[t]);
    float2 s1 = __half22float2(ad2[t + 16]);
    float2 s2 = __half22float2(ad2[t + 32]);
    const float dd2 = dd * dd;
    float a0x = s0.x * dd2, a0y = s0.y * dd2;
    float a1x = s1.x * dd2, a1y = s1.y * dd2;
    float a2x = s2.x * dd2, a2y = s2.y * dd2;
    int j = beg;
    for (; j + 7 < end; j += 8) {
        int2 e[8];
#pragma unroll
        for (int q = 0; q < 8; ++q) e[q] = ssrcw[j + q];
        float w[8];
        const __half2* ap[8];
#pragma unroll
        for (int q = 0; q < 8; ++q) {
            w[q] = __int_as_float(e[q].y);
            ap[q] = (const __half2*)(Ah + (size_t)e[q].x * HID);
        }
        __half2 g0[8], g1[8], g2[8];
#pragma unroll
        for (int q = 0; q < 8; ++q) {
            g0[q] = ap[q][t];
            g1[q] = ap[q][t + 16];
            g2[q] = ap[q][t + 32];
        }
#pragma unroll
        for (int q = 0; q < 8; ++q) {
            float2 f0 = __half22float2(g0[q]);
            float2 f1 = __half22float2(g1[q]);
            float2 f2 = __half22float2(g2[q]);
            a0x += f0.x * w[q]; a0y += f0.y * w[q];
            a1x += f1.x * w[q]; a1y += f1.y * w[q];
            a2x += f2.x * w[q]; a2y += f2.y * w[q];
        }
    }
    for (; j < end; ++j) {
        int2 e0 = ssrcw[j];
        float w0 = __int_as_float(e0.y);
        const __half2* a0 = (const __half2*)(Ah + (size_t)e0.x * HID);
        float2 f0 = __half22float2(a0[t]);
        float2 f1 = __half22float2(a0[t + 16]);
        float2 f2 = __half22float2(a0[t + 32]);
        a0x += f0.x * w0; a0y += f0.y * w0;
        a1x += f1.x * w0; a1y += f1.y * w0;
        a2x += f2.x * w0; a2y += f2.y * w0;
    }
    const float2* b2p = (const float2*)bias;
    float2 b0 = b2p[t], b1 = b2p[t + 16], b2 = b2p[t + 32];
    float h0x = fmaxf(a0x + b0.x, 0.f), h0y = fmaxf(a0y + b0.y, 0.f);
    float h1x = fmaxf(a1x + b1.x, 0.f), h1y = fmaxf(a1y + b1.y, 0.f);
    float h2x = fmaxf(a2x + b2.x, 0.f), h2y = fmaxf(a2y + b2.y, 0.f);
    __half2* o2 = (__half2*)(outh + (size_t)d * HID);
    o2[t]      = __floats2half2_rn(h0x, h0y);
    o2[t + 16] = __floats2half2_rn(h1x, h1y);
    o2[t + 32] = __floats2half2_rn(h2x, h2y);

    const int woff = (PHASE == 1) ? 0 : 96;
    const float2* wn2 = (const float2*)(Wn + woff);
    float2 w0v = wn2[t], w1v = wn2[t + 16], w2v = wn2[t + 32];
    float partial = h0x * w0v.x + h0y * w0v.y + h1x * w1v.x + h1y * w1v.y +
                    h2x * w2v.x + h2y * w2v.y;
#pragma unroll
    for (int m = 8; m; m >>= 1) partial += __shfl_down(partial, m, 16);
    if (t == 0) {
        if (PHASE == 1) nodeOut[d] = partial + bn[0];
        else            nodeOut[d] += partial;
    }
}

// ---------------- graph pooling + graph head (fp16 H inputs) ----------------
// 768 threads: 4 node-ways x 192 features
__global__ __launch_bounds__(768) void k_pool(const __half* __restrict__ h1,
                                              const __half* __restrict__ h2,
                                              const int* __restrict__ batch,
                                              const float* __restrict__ Wg,
                                              const float* __restrict__ bg,
                                              float* __restrict__ out) {
    int g = blockIdx.x;
    int tid = threadIdx.x;       // 0..767
    int way = tid / 192;         // 0..3
    int f = tid - way * 192;     // 0..191

    int lo = 0, hi = NN;
    while (lo < hi) { int mid = (lo + hi) >> 1; if (batch[mid] < g) lo = mid + 1; else hi = mid; }
    int start = lo;
    hi = NN;
    while (lo < hi) { int mid = (lo + hi) >> 1; if (batch[mid] < g + 1) lo = mid + 1; else hi = mid; }
    int end = lo;

    const __half* hsrc = (f < HID) ? h1 : h2;
    int ff = (f < HID) ? f : f - HID;
    float sum = 0.f, mx = 0.f;  // h >= 0 post-relu
    for (int n = start + way; n < end; n += 4) {
        float v = __half2float(hsrc[(size_t)n * HID + ff]);
        sum += v;
        mx = fmaxf(mx, v);
    }
    __shared__ float rsum[4][192];
    __shared__ float rmax[4][192];
    rsum[way][f] = sum;
    rmax[way][f] = mx;
    __syncthreads();
    if (way == 0) {
        sum = rsum[0][f] + rsum[1][f] + rsum[2][f] + rsum[3][f];
        mx = fmaxf(fmaxf(rmax[0][f], rmax[1][f]), fmaxf(rmax[2][f], rmax[3][f]));
        float cnt = (float)(end - start);
        float mean = sum / fmaxf(cnt, 1.0f);
        rsum[0][f] = mean * Wg[f] + mx * Wg[192 + f];
    }
    __syncthreads();
    if (tid < 64) {
        float acc = rsum[0][tid] + rsum[0][tid + 64] + rsum[0][tid + 128];
#pragma unroll
        for (int m = 32; m; m >>= 1) acc += __shfl_down(acc, m, 64);
        if (tid == 0) out[g] = acc + bg[0];
    }
}

extern "C" void kernel_launch(void* const* d_in, const int* in_sizes, int n_in,
                              void* d_out, int out_size, void* d_ws, size_t ws_size,
                              hipStream_t stream) {
    const float* x    = (const float*)d_in[0];
    const int*   ei   = (const int*)d_in[1];
    const int*   srcp = ei;
    const int*   dstp = ei + NE;
    const int*   batch = (const int*)d_in[2];
    const float* W1 = (const float*)d_in[3];
    const float* b1 = (const float*)d_in[4];
    const float* W2 = (const float*)d_in[5];
    const float* b2 = (const float*)d_in[6];
    const float* Wn = (const float*)d_in[7];
    const float* bn = (const float*)d_in[8];
    const float* Wg = (const float*)d_in[9];
    const float* bg = (const float*)d_in[10];
    float* out = (float*)d_out;

    char* p = (char*)d_ws;
    auto alloc = [&](size_t bytes) {
        char* r = p;
        p += (bytes + 255) & ~(size_t)255;
        return (void*)r;
    };
    float*  dis    = (float*)alloc(NN * 4);
    int*    off    = (int*)alloc((NN + 1) * 4);
    int*    cur    = (int*)alloc(NN * 4);
    int*    bsum   = (int*)alloc(128 * 4);
    int2*   ssrcw  = (int2*)alloc((size_t)NE * 8);
    __half* Ah     = (__half*)alloc((size_t)NN * HID * 2);   // hw buffer (both convs)
    __half* H1h    = (__half*)alloc((size_t)NN * HID * 2);
    __half* H2h    = (__half*)alloc((size_t)NN * HID * 2);
    __half* W2frag = (__half*)alloc(9216 * 2);

    const int TPB = 256;
    const int nScan = NN + 1;
    const int nbScan = (nScan + 1023) / 1024;    // 98

    // prelude
    k_zero_pack<<<ZERO_BLOCKS + 5, TPB, 0, stream>>>(off, W2, W2frag);
    k_hist<<<(NE + TPB - 1) / TPB, TPB, 0, stream>>>(dstp, off);
    k_scan1<<<nbScan, 256, 0, stream>>>(off, bsum, dis, cur, nScan);
    k_scan3<<<nbScan, 256, 0, stream>>>(off, bsum, nScan);

    // FUSED: gemm1 ∥ reorder
    k_gemm1_reorder<<<GEMM1_BLOCKS + REORDER_BLOCKS, 256, 0, stream>>>(
        x, W1, Ah, srcp, dstp, off, cur, dis, ssrcw);

    const int aggThreads = NN * 16;
    float* nodeOut = out + NG;

    // conv1 aggregate (16-lane half2): H1h ; nodeOut partial 1
    k_agg<1><<<(aggThreads + TPB - 1) / TPB, TPB, 0, stream>>>(Ah, ssrcw, off, dis, b1, Wn, bn, H1h, nodeOut);

    // conv2 transform (MFMA, standalone)
    k_gemm2<<<G2_BLOCKS, 256, 0, stream>>>(H1h, W2frag, Ah);

    // conv2 aggregate: H2h ; nodeOut partial 2
    k_agg<2><<<(aggThreads + TPB - 1) / TPB, TPB, 0, stream>>>(Ah, ssrcw, off, dis, b2, Wn, bn, H2h, nodeOut);

    // pooling + graph head
    k_pool<<<NG, 768, 0, stream>>>(H1h, H2h, batch, Wg, bg, out);
}